// Round 5
// baseline (541.828 us; speedup 1.0000x reference)
//
#include <hip/hip_runtime.h>

// DGMC top-k correspondence, MI355X — bf16 MFMA candidate GEMM + f64 refine.
// Phase 0: convert h_t fp32 -> bf16, granule-swizzled (phys g holds logical g^(row&31)).
// Phase 1: S^T tiles via mfma_f32_32x32x16_bf16 (A=h_t from LDS, B=h_s in regs).
//          Per-lane top-10 as SORTED PACKED uints: key = (ordered_f32 & ~0x3FFF) | t.
//          32-row LDS double-buffer (32 KB) -> 5 blocks/CU for VALU latency hiding.
// Phase 2: per-row merge of packed chains -> top-16 candidate indices.
// Phase 3: f64 re-eval, lane-parallel rank computation, softmax, scatter write.

typedef __attribute__((ext_vector_type(8)))  short bf16x8;
typedef __attribute__((ext_vector_type(16))) float f32x16;
typedef __attribute__((ext_vector_type(8)))  unsigned short u16x8;

#define K_TOP 10
#define CAND_M 16
#define CDIM 256

#define GLD_LDS(src, dst) \
    __builtin_amdgcn_global_load_lds((const __attribute__((address_space(1))) void*)(src), \
                                     (__attribute__((address_space(3))) void*)(dst), 16, 0, 0)

__device__ __forceinline__ unsigned short f2bf(float f) {
    unsigned u = __float_as_uint(f);
    u += 0x7fffu + ((u >> 16) & 1u);      // RNE
    return (unsigned short)(u >> 16);
}

__device__ __forceinline__ unsigned umax2(unsigned a, unsigned b) { return a > b ? a : b; }

__device__ __forceinline__ unsigned umax16(const unsigned (&p)[16]) {
    unsigned a = umax2(umax2(umax2(p[0], p[1]), umax2(p[2], p[3])),
                       umax2(umax2(p[4], p[5]), umax2(p[6], p[7])));
    unsigned b = umax2(umax2(umax2(p[8], p[9]), umax2(p[10], p[11])),
                       umax2(umax2(p[12], p[13]), umax2(p[14], p[15])));
    return umax2(a, b);
}

// Branchless ripple-insert of v into descending-sorted tv. No-op when v <= tv[K-1].
template <int K>
__device__ __forceinline__ void sorted_insert(unsigned (&tv)[K], unsigned v) {
    bool m[K];
#pragma unroll
    for (int q = 0; q < K; ++q) m[q] = tv[q] >= v;
    unsigned nv[K];
    nv[0] = m[0] ? tv[0] : v;
#pragma unroll
    for (int q = 1; q < K; ++q)
        nv[q] = m[q] ? tv[q] : (m[q - 1] ? v : tv[q - 1]);
#pragma unroll
    for (int q = 0; q < K; ++q) tv[q] = nv[q];
}

// ---------- Phase 0: fp32 -> bf16 with per-row granule XOR swizzle ----------
__global__ void conv_swz(const float* __restrict__ in, unsigned short* __restrict__ out, int N)
{
    int gid = blockIdx.x * blockDim.x + threadIdx.x;
    int row = gid >> 5, gl = gid & 31;
    if (row >= N) return;
    const float4* src = (const float4*)(in + (size_t)row * CDIM + gl * 8);
    float4 a0 = src[0], a1 = src[1];
    u16x8 o;
    o[0] = f2bf(a0.x); o[1] = f2bf(a0.y); o[2] = f2bf(a0.z); o[3] = f2bf(a0.w);
    o[4] = f2bf(a1.x); o[5] = f2bf(a1.y); o[6] = f2bf(a1.z); o[7] = f2bf(a1.w);
    *(u16x8*)(out + (size_t)row * CDIM + ((gl ^ (row & 31)) * 8)) = o;
}

// ---------- Phase 1: MFMA GEMM + per-lane packed top-10 ----------
__device__ __forceinline__ void stage32(const unsigned short* __restrict__ htb,
                                        short* ldsbuf, int tbase, int Nt,
                                        int tid, int wbase) {
#pragma unroll
    for (int it = 0; it < 4; ++it) {
        int pp = it * 256 + tid;
        int rr = pp >> 5, gg = pp & 31;
        int grow = tbase + rr; grow = grow < Nt ? grow : Nt - 1;
        GLD_LDS(htb + (size_t)grow * CDIM + gg * 8, ldsbuf + (it * 256 + wbase) * 8);
    }
}

// block = 256 thr = 4 waves; wave w owns 32 s-cols (block spans 128 s).
// LDS: 2 x (32 t-rows x 256 bf16) = 32 KB double buffer -> 5 blocks/CU.
__global__ __launch_bounds__(256, 5) void topk_mfma(
    const float* __restrict__ ehs, const float* __restrict__ rhs_,
    const unsigned short* __restrict__ ehtb, const unsigned short* __restrict__ rhtb,
    unsigned* __restrict__ partials, int Ns, int Nt, int Pt, int SB, int PS)
{
    __shared__ short ldsT[2 * 32 * 256];

    const int tid = threadIdx.x;
    const int w = tid >> 6, lane = tid & 63;
    const int l5 = lane & 31, hi = lane >> 5;
    const int wbase = tid & ~63;
    const int CH = 2 * Pt;

    const int bid  = blockIdx.x;
    const int prob = bid / (Pt * SB);
    const int rem  = bid % (Pt * SB);
    const int p    = rem / SB, sb = rem % SB;

    const float* hs = prob ? rhs_ : ehs;
    const unsigned short* htb = prob ? rhtb : ehtb;

    const int srow = sb * 128 + w * 32 + l5;
    const int srd  = srow < Ns ? srow : Ns - 1;

    // B-panel: h_s[srd][kk*16 + hi*8 + j], j=0..7 -> 16 frags (64 VGPRs), persistent.
    bf16x8 b[16];
#pragma unroll
    for (int kk = 0; kk < 16; ++kk) {
        const float4* sp = (const float4*)(hs + (size_t)srd * CDIM + kk * 16 + hi * 8);
        float4 f0 = sp[0], f1 = sp[1];
        bf16x8 t;
        t[0] = (short)f2bf(f0.x); t[1] = (short)f2bf(f0.y);
        t[2] = (short)f2bf(f0.z); t[3] = (short)f2bf(f0.w);
        t[4] = (short)f2bf(f1.x); t[5] = (short)f2bf(f1.y);
        t[6] = (short)f2bf(f1.z); t[7] = (short)f2bf(f1.w);
        b[kk] = t;
    }

    const int t0 = p * PS;
    const int t1 = min(t0 + PS, Nt);

    unsigned tvp[K_TOP];
#pragma unroll
    for (int q = 0; q < K_TOP; ++q) tvp[q] = 0u;

    const int rounds = (t1 > t0) ? ((t1 - t0 + 31) >> 5) : 0;

    if (rounds > 0) {
        stage32(htb, ldsT, t0, Nt, tid, wbase);
        __syncthreads();

        for (int rd = 0; rd < rounds; ++rd) {
            const int cur = rd & 1;
            const int tb  = t0 + rd * 32;
            if (rd + 1 < rounds)
                stage32(htb, ldsT + (cur ^ 1) * 8192, tb + 32, Nt, tid, wbase);

            const bool guard = (tb + 32 > t1);
            const short* rowp = ldsT + cur * 8192 + l5 * CDIM;
            f32x16 acc = {};
#pragma unroll
            for (int kk = 0; kk < 16; ++kk) {
                // A-frag: row = l5 (t-local), k = kk*16 + hi*8 + j; unswizzle granule
                bf16x8 a = *(const bf16x8*)(rowp + (((kk * 2 + hi) ^ l5) * 8));
                acc = __builtin_amdgcn_mfma_f32_32x32x16_bf16(a, b[kk], acc, 0, 0, 0);
            }
            // ---- packed scan: one s-col per lane, 16 t-values ----
            const int tb2 = tb + 4 * hi;
            unsigned pu[16];
#pragma unroll
            for (int r = 0; r < 16; ++r) {
                unsigned u = __float_as_uint(acc[r]);
                u ^= (unsigned)((int)u >> 31) | 0x80000000u;   // order-preserving
                int t = tb2 + (r & 3) + 8 * (r >> 2);
                pu[r] = (u & 0xFFFFC000u) | (unsigned)t;       // 18 value bits | 14 idx bits
            }
            if (guard) {
#pragma unroll
                for (int r = 0; r < 16; ++r) {
                    int t = tb2 + (r & 3) + 8 * (r >> 2);
                    if (t >= t1) pu[r] = 0u;
                }
            }
            unsigned mx = umax16(pu);
            while (__any((int)(mx > tvp[K_TOP - 1]))) {
                sorted_insert<K_TOP>(tvp, mx);     // no-op for lanes with mx <= tvp[9]
#pragma unroll
                for (int r = 0; r < 16; ++r)
                    pu[r] = (pu[r] == mx) ? 0u : pu[r];
                mx = umax16(pu);
            }
            __syncthreads();
        }
    }

    // chain write: layout [prob][chain][q][Ns], coalesced across srow
    if (srow < Ns) {
        unsigned* wp = partials + ((size_t)(prob * CH + (p * 2 + hi)) * K_TOP) * Ns + srow;
#pragma unroll
        for (int q = 0; q < K_TOP; ++q) wp[(size_t)q * Ns] = tvp[q];
    }
}

// ---------- Phase 2: merge packed chains -> top-16 candidate indices ----------
__global__ void topk_mergecand(const unsigned* __restrict__ partials, int* __restrict__ cand,
                               int Ns, int CH)
{
    int g = blockIdx.x * blockDim.x + threadIdx.x;
    if (g >= 2 * Ns) return;
    const int prob = g >= Ns ? 1 : 0;
    const int row  = g - prob * Ns;
    const unsigned* src = partials + ((size_t)prob * CH * K_TOP) * Ns + row;

    unsigned tvp[CAND_M];
#pragma unroll
    for (int q = 0; q < CAND_M; ++q) tvp[q] = 0u;

    for (int c = 0; c < CH; ++c) {
#pragma unroll
        for (int q = 0; q < K_TOP; ++q) {
            unsigned v = src[(size_t)(c * K_TOP + q) * Ns];
            if (v > tvp[CAND_M - 1]) sorted_insert<CAND_M>(tvp, v);
        }
    }
    int* dst = cand + (size_t)g * CAND_M;
#pragma unroll
    for (int q = 0; q < CAND_M; ++q) dst[q] = (int)(tvp[q] & 0x3FFFu);
}

// ---------- Phase 3: f64 refine, lane-parallel rank, softmax, scatter ----------
// One wave per row. lane = (c = lane>>4) * 16 + (m = lane&15):
// candidate m, element chunk c (64 elems). All candidates distinct by construction.
__global__ __launch_bounds__(256) void topk_refine(
    const float* __restrict__ ehs, const float* __restrict__ eht,
    const float* __restrict__ rhs_, const float* __restrict__ rht,
    const int* __restrict__ cand, float* __restrict__ out, int Ns)
{
    __shared__ double svd[4][CAND_M];
    __shared__ int    sci[4][CAND_M];

    const int wiw  = threadIdx.x >> 6;
    const int wid  = blockIdx.x * 4 + wiw;
    const int lane = threadIdx.x & 63;
    const int m = lane & 15, c = lane >> 4;
    if (wid >= 2 * Ns) return;

    const int prob = wid < Ns ? 0 : 1;
    const int row  = prob ? (wid - Ns) : wid;
    const float* hs = prob ? rhs_ : ehs;
    const float* ht = prob ? rht  : eht;

    const int t = cand[(size_t)wid * CAND_M + m];
    const float4* ap = (const float4*)(hs + (size_t)row * CDIM + c * 64);
    const float4* bp = (const float4*)(ht + (size_t)t   * CDIM + c * 64);

    double s = 0.0;
#pragma unroll
    for (int i = 0; i < 16; ++i) {
        float4 av = ap[i], bv = bp[i];
        s += (double)av.x * (double)bv.x + (double)av.y * (double)bv.y
           + (double)av.z * (double)bv.z + (double)av.w * (double)bv.w;
    }
    s += __shfl_xor(s, 16, 64);
    s += __shfl_xor(s, 32, 64);          // all lanes: full dot for candidate m

    if (c == 0) { svd[wiw][m] = s; sci[wiw][m] = t; }
    // same-wave LDS write->read: DS ops are wave-ordered; compiler inserts lgkm waits.

    int rank = 0;
    double vmax = -1.0e300;
#pragma unroll
    for (int j = 0; j < CAND_M; ++j) {
        double vj = svd[wiw][j]; int cj = sci[wiw][j];
        bool better = (vj > s) || (vj == s && cj < t);
        rank += better ? 1 : 0;
        vmax = fmax(vmax, vj);
    }
    float ex = (rank < K_TOP) ? __expf((float)(s - vmax)) : 0.f;
    float ssum = ex;
    ssum += __shfl_xor(ssum, 1, 64);
    ssum += __shfl_xor(ssum, 2, 64);
    ssum += __shfl_xor(ssum, 4, 64);
    ssum += __shfl_xor(ssum, 8, 64);     // sum over the 16 candidates in this c-group

    if (c == 0 && rank < K_TOP) {
        size_t nsk = (size_t)Ns * K_TOP;
        size_t so  = (size_t)wid * K_TOP;
        out[so + rank] = ex / ssum;
        out[2 * nsk + so + rank] = (float)t;
    }
}

extern "C" void kernel_launch(void* const* d_in, const int* in_sizes, int n_in,
                              void* d_out, int out_size, void* d_ws, size_t ws_size,
                              hipStream_t stream) {
    (void)n_in; (void)out_size;
    const float* eh_s = (const float*)d_in[0];
    const float* eh_t = (const float*)d_in[1];
    const float* rh_s = (const float*)d_in[2];
    const float* rh_t = (const float*)d_in[3];
    // d_in[4] is k (=10), compile-time constant here.

    const int Ns = in_sizes[0] / CDIM;
    const int Nt = in_sizes[1] / CDIM;
    const int SB = (Ns + 127) / 128;

    const size_t htbElems = (size_t)Nt * CDIM;          // per array, ushorts
    const size_t htbBytes = 2 * htbElems * 2;
    const size_t candBytes = (size_t)2 * Ns * CAND_M * sizeof(int);

    int Pt = 8;
    while (Pt > 1 &&
           htbBytes + (size_t)2 * Ns * (2 * Pt) * K_TOP * sizeof(unsigned) + candBytes > ws_size)
        Pt >>= 1;
    const int PS = (int)((((size_t)Nt + Pt - 1) / Pt + 31) & ~(size_t)31);

    unsigned short* htb_e = (unsigned short*)d_ws;
    unsigned short* htb_r = htb_e + htbElems;
    unsigned* partials = (unsigned*)(htb_r + htbElems);
    int*  cand = (int*)((char*)partials + (size_t)2 * Ns * (2 * Pt) * K_TOP * sizeof(unsigned));

    dim3 block(256);

    // Phase 0: convert both h_t arrays (swizzled bf16)
    int convBlocks = (Nt * 32 + 255) / 256;
    conv_swz<<<dim3(convBlocks), block, 0, stream>>>(eh_t, htb_e, Nt);
    conv_swz<<<dim3(convBlocks), block, 0, stream>>>(rh_t, htb_r, Nt);

    // Phase 1: MFMA GEMM + packed top-10 chains
    topk_mfma<<<dim3(2 * Pt * SB), block, 0, stream>>>(eh_s, rh_s, htb_e, htb_r,
                                                       partials, Ns, Nt, Pt, SB, PS);

    // Phase 2: merge -> candidates
    int nrows = 2 * Ns;
    topk_mergecand<<<dim3((nrows + 255) / 256), block, 0, stream>>>(partials, cand,
                                                                    Ns, 2 * Pt);

    // Phase 3: f64 refine + softmax + scatter write
    topk_refine<<<dim3((nrows + 3) / 4), block, 0, stream>>>(eh_s, eh_t, rh_s, rh_t,
                                                             cand, (float*)d_out, Ns);
}

// Round 6
// 368.132 us; speedup vs baseline: 1.4718x; 1.4718x over previous
//
#include <hip/hip_runtime.h>

// DGMC top-k correspondence, MI355X — bf16 MFMA candidate GEMM + f64 refine.
// Phase 0: convert h_t fp32 -> bf16, granule-swizzled (phys g holds logical g^(row&31)).
// Phase 1: S^T tiles via mfma_f32_32x32x16_bf16 (A=h_t from LDS, B=h_s in regs).
//          Per-lane top-10 as SORTED PACKED uints: key = (ordered_f32 & ~0x3FFF) | t.
//          32-row LDS double-buffer (32 KB). launch_bounds(256,4): VGPR cap 128 —
//          (256,5) capped at ~102 and SPILLED the 64-VGPR B-panel (round-5: 785 MB
//          scratch traffic, 1.8x regression). 4 blocks/CU via LDS+VGPR, no spill.
// Phase 2: per-row merge of packed chains -> top-16 candidate indices.
// Phase 3: f64 re-eval, lane-parallel rank computation, softmax, scatter write.

typedef __attribute__((ext_vector_type(8)))  short bf16x8;
typedef __attribute__((ext_vector_type(16))) float f32x16;
typedef __attribute__((ext_vector_type(8)))  unsigned short u16x8;

#define K_TOP 10
#define CAND_M 16
#define CDIM 256

#define GLD_LDS(src, dst) \
    __builtin_amdgcn_global_load_lds((const __attribute__((address_space(1))) void*)(src), \
                                     (__attribute__((address_space(3))) void*)(dst), 16, 0, 0)

__device__ __forceinline__ unsigned short f2bf(float f) {
    unsigned u = __float_as_uint(f);
    u += 0x7fffu + ((u >> 16) & 1u);      // RNE
    return (unsigned short)(u >> 16);
}

__device__ __forceinline__ unsigned umax2(unsigned a, unsigned b) { return a > b ? a : b; }

__device__ __forceinline__ unsigned umax16(const unsigned (&p)[16]) {
    unsigned a = umax2(umax2(umax2(p[0], p[1]), umax2(p[2], p[3])),
                       umax2(umax2(p[4], p[5]), umax2(p[6], p[7])));
    unsigned b = umax2(umax2(umax2(p[8], p[9]), umax2(p[10], p[11])),
                       umax2(umax2(p[12], p[13]), umax2(p[14], p[15])));
    return umax2(a, b);
}

// Branchless ripple-insert of v into descending-sorted tv. No-op when v <= tv[K-1].
template <int K>
__device__ __forceinline__ void sorted_insert(unsigned (&tv)[K], unsigned v) {
    bool m[K];
#pragma unroll
    for (int q = 0; q < K; ++q) m[q] = tv[q] >= v;
    unsigned nv[K];
    nv[0] = m[0] ? tv[0] : v;
#pragma unroll
    for (int q = 1; q < K; ++q)
        nv[q] = m[q] ? tv[q] : (m[q - 1] ? v : tv[q - 1]);
#pragma unroll
    for (int q = 0; q < K; ++q) tv[q] = nv[q];
}

// ---------- Phase 0: fp32 -> bf16 with per-row granule XOR swizzle ----------
__global__ void conv_swz(const float* __restrict__ in, unsigned short* __restrict__ out, int N)
{
    int gid = blockIdx.x * blockDim.x + threadIdx.x;
    int row = gid >> 5, gl = gid & 31;
    if (row >= N) return;
    const float4* src = (const float4*)(in + (size_t)row * CDIM + gl * 8);
    float4 a0 = src[0], a1 = src[1];
    u16x8 o;
    o[0] = f2bf(a0.x); o[1] = f2bf(a0.y); o[2] = f2bf(a0.z); o[3] = f2bf(a0.w);
    o[4] = f2bf(a1.x); o[5] = f2bf(a1.y); o[6] = f2bf(a1.z); o[7] = f2bf(a1.w);
    *(u16x8*)(out + (size_t)row * CDIM + ((gl ^ (row & 31)) * 8)) = o;
}

// ---------- Phase 1: MFMA GEMM + per-lane packed top-10 ----------
__device__ __forceinline__ void stage32(const unsigned short* __restrict__ htb,
                                        short* ldsbuf, int tbase, int Nt,
                                        int tid, int wbase) {
#pragma unroll
    for (int it = 0; it < 4; ++it) {
        int pp = it * 256 + tid;
        int rr = pp >> 5, gg = pp & 31;
        int grow = tbase + rr; grow = grow < Nt ? grow : Nt - 1;
        GLD_LDS(htb + (size_t)grow * CDIM + gg * 8, ldsbuf + (it * 256 + wbase) * 8);
    }
}

// block = 256 thr = 4 waves; wave w owns 32 s-cols (block spans 128 s).
// LDS: 2 x (32 t-rows x 256 bf16) = 32 KB double buffer.
__global__ __launch_bounds__(256, 4) void topk_mfma(
    const float* __restrict__ ehs, const float* __restrict__ rhs_,
    const unsigned short* __restrict__ ehtb, const unsigned short* __restrict__ rhtb,
    unsigned* __restrict__ partials, int Ns, int Nt, int Pt, int SB, int PS)
{
    __shared__ short ldsT[2 * 32 * 256];

    const int tid = threadIdx.x;
    const int w = tid >> 6, lane = tid & 63;
    const int l5 = lane & 31, hi = lane >> 5;
    const int wbase = tid & ~63;
    const int CH = 2 * Pt;

    const int bid  = blockIdx.x;
    const int prob = bid / (Pt * SB);
    const int rem  = bid % (Pt * SB);
    const int p    = rem / SB, sb = rem % SB;

    const float* hs = prob ? rhs_ : ehs;
    const unsigned short* htb = prob ? rhtb : ehtb;

    const int srow = sb * 128 + w * 32 + l5;
    const int srd  = srow < Ns ? srow : Ns - 1;

    // B-panel: h_s[srd][kk*16 + hi*8 + j], j=0..7 -> 16 frags (64 VGPRs), persistent.
    bf16x8 b[16];
#pragma unroll
    for (int kk = 0; kk < 16; ++kk) {
        const float4* sp = (const float4*)(hs + (size_t)srd * CDIM + kk * 16 + hi * 8);
        float4 f0 = sp[0], f1 = sp[1];
        bf16x8 t;
        t[0] = (short)f2bf(f0.x); t[1] = (short)f2bf(f0.y);
        t[2] = (short)f2bf(f0.z); t[3] = (short)f2bf(f0.w);
        t[4] = (short)f2bf(f1.x); t[5] = (short)f2bf(f1.y);
        t[6] = (short)f2bf(f1.z); t[7] = (short)f2bf(f1.w);
        b[kk] = t;
    }

    const int t0 = p * PS;
    const int t1 = min(t0 + PS, Nt);

    unsigned tvp[K_TOP];
#pragma unroll
    for (int q = 0; q < K_TOP; ++q) tvp[q] = 0u;

    const int rounds = (t1 > t0) ? ((t1 - t0 + 31) >> 5) : 0;

    if (rounds > 0) {
        stage32(htb, ldsT, t0, Nt, tid, wbase);
        __syncthreads();

        for (int rd = 0; rd < rounds; ++rd) {
            const int cur = rd & 1;
            const int tb  = t0 + rd * 32;
            if (rd + 1 < rounds)
                stage32(htb, ldsT + (cur ^ 1) * 8192, tb + 32, Nt, tid, wbase);

            const bool guard = (tb + 32 > t1);
            const short* rowp = ldsT + cur * 8192 + l5 * CDIM;
            f32x16 acc = {};
#pragma unroll
            for (int kk = 0; kk < 16; ++kk) {
                // A-frag: row = l5 (t-local), k = kk*16 + hi*8 + j; unswizzle granule
                bf16x8 a = *(const bf16x8*)(rowp + (((kk * 2 + hi) ^ l5) * 8));
                acc = __builtin_amdgcn_mfma_f32_32x32x16_bf16(a, b[kk], acc, 0, 0, 0);
            }
            // ---- packed scan: one s-col per lane, 16 t-values ----
            const int tb2 = tb + 4 * hi;
            unsigned pu[16];
#pragma unroll
            for (int r = 0; r < 16; ++r) {
                unsigned u = __float_as_uint(acc[r]);
                u ^= (unsigned)((int)u >> 31) | 0x80000000u;   // order-preserving
                int t = tb2 + (r & 3) + 8 * (r >> 2);
                pu[r] = (u & 0xFFFFC000u) | (unsigned)t;       // 18 value bits | 14 idx bits
            }
            if (guard) {
#pragma unroll
                for (int r = 0; r < 16; ++r) {
                    int t = tb2 + (r & 3) + 8 * (r >> 2);
                    if (t >= t1) pu[r] = 0u;
                }
            }
            unsigned mx = umax16(pu);
            while (__any((int)(mx > tvp[K_TOP - 1]))) {
                sorted_insert<K_TOP>(tvp, mx);     // no-op for lanes with mx <= tvp[9]
#pragma unroll
                for (int r = 0; r < 16; ++r)
                    pu[r] = (pu[r] == mx) ? 0u : pu[r];
                mx = umax16(pu);
            }
            __syncthreads();
        }
    }

    // chain write: layout [prob][chain][q][Ns], coalesced across srow
    if (srow < Ns) {
        unsigned* wp = partials + ((size_t)(prob * CH + (p * 2 + hi)) * K_TOP) * Ns + srow;
#pragma unroll
        for (int q = 0; q < K_TOP; ++q) wp[(size_t)q * Ns] = tvp[q];
    }
}

// ---------- Phase 2: merge packed chains -> top-16 candidate indices ----------
__global__ void topk_mergecand(const unsigned* __restrict__ partials, int* __restrict__ cand,
                               int Ns, int CH)
{
    int g = blockIdx.x * blockDim.x + threadIdx.x;
    if (g >= 2 * Ns) return;
    const int prob = g >= Ns ? 1 : 0;
    const int row  = g - prob * Ns;
    const unsigned* src = partials + ((size_t)prob * CH * K_TOP) * Ns + row;

    unsigned tvp[CAND_M];
#pragma unroll
    for (int q = 0; q < CAND_M; ++q) tvp[q] = 0u;

    for (int c = 0; c < CH; ++c) {
#pragma unroll
        for (int q = 0; q < K_TOP; ++q) {
            unsigned v = src[(size_t)(c * K_TOP + q) * Ns];
            if (v > tvp[CAND_M - 1]) sorted_insert<CAND_M>(tvp, v);
        }
    }
    int* dst = cand + (size_t)g * CAND_M;
#pragma unroll
    for (int q = 0; q < CAND_M; ++q) dst[q] = (int)(tvp[q] & 0x3FFFu);
}

// ---------- Phase 3: f64 refine, lane-parallel rank, softmax, scatter ----------
// One wave per row. lane = (c = lane>>4) * 16 + (m = lane&15):
// candidate m, element chunk c (64 elems). All candidates distinct by construction.
__global__ __launch_bounds__(256) void topk_refine(
    const float* __restrict__ ehs, const float* __restrict__ eht,
    const float* __restrict__ rhs_, const float* __restrict__ rht,
    const int* __restrict__ cand, float* __restrict__ out, int Ns)
{
    __shared__ double svd[4][CAND_M];
    __shared__ int    sci[4][CAND_M];

    const int wiw  = threadIdx.x >> 6;
    const int wid  = blockIdx.x * 4 + wiw;
    const int lane = threadIdx.x & 63;
    const int m = lane & 15, c = lane >> 4;
    if (wid >= 2 * Ns) return;

    const int prob = wid < Ns ? 0 : 1;
    const int row  = prob ? (wid - Ns) : wid;
    const float* hs = prob ? rhs_ : ehs;
    const float* ht = prob ? rht  : eht;

    const int t = cand[(size_t)wid * CAND_M + m];
    const float4* ap = (const float4*)(hs + (size_t)row * CDIM + c * 64);
    const float4* bp = (const float4*)(ht + (size_t)t   * CDIM + c * 64);

    double s = 0.0;
#pragma unroll
    for (int i = 0; i < 16; ++i) {
        float4 av = ap[i], bv = bp[i];
        s += (double)av.x * (double)bv.x + (double)av.y * (double)bv.y
           + (double)av.z * (double)bv.z + (double)av.w * (double)bv.w;
    }
    s += __shfl_xor(s, 16, 64);
    s += __shfl_xor(s, 32, 64);          // all lanes: full dot for candidate m

    if (c == 0) { svd[wiw][m] = s; sci[wiw][m] = t; }
    // same-wave LDS write->read: DS ops are wave-ordered; compiler inserts lgkm waits.

    int rank = 0;
    double vmax = -1.0e300;
#pragma unroll
    for (int j = 0; j < CAND_M; ++j) {
        double vj = svd[wiw][j]; int cj = sci[wiw][j];
        bool better = (vj > s) || (vj == s && cj < t);
        rank += better ? 1 : 0;
        vmax = fmax(vmax, vj);
    }
    float ex = (rank < K_TOP) ? __expf((float)(s - vmax)) : 0.f;
    float ssum = ex;
    ssum += __shfl_xor(ssum, 1, 64);
    ssum += __shfl_xor(ssum, 2, 64);
    ssum += __shfl_xor(ssum, 4, 64);
    ssum += __shfl_xor(ssum, 8, 64);     // sum over the 16 candidates in this c-group

    if (c == 0 && rank < K_TOP) {
        size_t nsk = (size_t)Ns * K_TOP;
        size_t so  = (size_t)wid * K_TOP;
        out[so + rank] = ex / ssum;
        out[2 * nsk + so + rank] = (float)t;
    }
}

extern "C" void kernel_launch(void* const* d_in, const int* in_sizes, int n_in,
                              void* d_out, int out_size, void* d_ws, size_t ws_size,
                              hipStream_t stream) {
    (void)n_in; (void)out_size;
    const float* eh_s = (const float*)d_in[0];
    const float* eh_t = (const float*)d_in[1];
    const float* rh_s = (const float*)d_in[2];
    const float* rh_t = (const float*)d_in[3];
    // d_in[4] is k (=10), compile-time constant here.

    const int Ns = in_sizes[0] / CDIM;
    const int Nt = in_sizes[1] / CDIM;
    const int SB = (Ns + 127) / 128;

    const size_t htbElems = (size_t)Nt * CDIM;          // per array, ushorts
    const size_t htbBytes = 2 * htbElems * 2;
    const size_t candBytes = (size_t)2 * Ns * CAND_M * sizeof(int);

    int Pt = 8;
    while (Pt > 1 &&
           htbBytes + (size_t)2 * Ns * (2 * Pt) * K_TOP * sizeof(unsigned) + candBytes > ws_size)
        Pt >>= 1;
    const int PS = (int)((((size_t)Nt + Pt - 1) / Pt + 31) & ~(size_t)31);

    unsigned short* htb_e = (unsigned short*)d_ws;
    unsigned short* htb_r = htb_e + htbElems;
    unsigned* partials = (unsigned*)(htb_r + htbElems);
    int*  cand = (int*)((char*)partials + (size_t)2 * Ns * (2 * Pt) * K_TOP * sizeof(unsigned));

    dim3 block(256);

    // Phase 0: convert both h_t arrays (swizzled bf16)
    int convBlocks = (Nt * 32 + 255) / 256;
    conv_swz<<<dim3(convBlocks), block, 0, stream>>>(eh_t, htb_e, Nt);
    conv_swz<<<dim3(convBlocks), block, 0, stream>>>(rh_t, htb_r, Nt);

    // Phase 1: MFMA GEMM + packed top-10 chains
    topk_mfma<<<dim3(2 * Pt * SB), block, 0, stream>>>(eh_s, rh_s, htb_e, htb_r,
                                                       partials, Ns, Nt, Pt, SB, PS);

    // Phase 2: merge -> candidates
    int nrows = 2 * Ns;
    topk_mergecand<<<dim3((nrows + 255) / 256), block, 0, stream>>>(partials, cand,
                                                                    Ns, 2 * Pt);

    // Phase 3: f64 refine + softmax + scatter write
    topk_refine<<<dim3((nrows + 3) / 4), block, 0, stream>>>(eh_s, eh_t, rh_s, rh_t,
                                                             cand, (float*)d_out, Ns);
}